// Round 8
// baseline (770.007 us; speedup 1.0000x reference)
//
#include <hip/hip_runtime.h>
#include <cstdint>

#define Hh 64
#define Tt 512
#define Dd 6
#define BB 4      // batch rows per block
#define NT 256    // 4 waves — ONE wave per SIMD, maximum per-wave ILP

typedef short bf16x8 __attribute__((ext_vector_type(8)));
typedef float f32x4  __attribute__((ext_vector_type(4)));

#define MF(A, B, C) C = __builtin_amdgcn_mfma_f32_16x16x32_bf16(A, B, C, 0, 0, 0)

__device__ __forceinline__ float sigm(float v){
  return __builtin_amdgcn_rcpf(1.f + __expf(-v));
}
__device__ __forceinline__ float tanh_(float v){
  return 1.f - 2.f*__builtin_amdgcn_rcpf(1.f + __expf(2.f*v));
}
__device__ __forceinline__ unsigned short f2bf(float f){
  union { float f; unsigned u; } v; v.f = f;
  unsigned r = v.u + 0x7FFFu + ((v.u >> 16) & 1u);   // RNE
  return (unsigned short)(r >> 16);
}
__device__ __forceinline__ float bf2f(unsigned short b){
  union { unsigned u; float f; } v; v.u = ((unsigned)b) << 16;
  return v.f;
}
__device__ __forceinline__ void split8(const float* w, bf16x8& hi, bf16x8& lo){
  #pragma unroll
  for (int i = 0; i < 8; ++i){
    unsigned short h_ = f2bf(w[i]);
    hi[i] = (short)h_;
    lo[i] = (short)f2bf(w[i] - bf2f(h_));
  }
}

// h stage: hsb[buf][layer] planes [16 n][64 j] bf16, byte ^= (n&7)<<4 swizzle.
// Rows 0-3 = h_hi(bs), 4-7 = h_lo(bs), 8-15 zero.
__global__ __launch_bounds__(NT, 1)
void lstm2_mfma(const float* __restrict__ x,
                const float* __restrict__ Wih0, const float* __restrict__ Whh0,
                const float* __restrict__ bih0, const float* __restrict__ bhh0,
                const float* __restrict__ Wih1, const float* __restrict__ Whh1,
                const float* __restrict__ bih1, const float* __restrict__ bhh1,
                const float* __restrict__ W1, const float* __restrict__ b1,
                const float* __restrict__ W2, const float* __restrict__ b2,
                float* __restrict__ out)
{
  __shared__ __align__(16) short hsb[2*2*1024];   // 8 KB [buf][layer][16][64]
  __shared__ __align__(16) float h1f[BB*Hh];
  __shared__ float zs[BB*32];

  const int tid  = threadIdx.x;
  const int lane = tid & 63;
  const int wid  = tid >> 6;        // wave 0..3
  const int lr   = lane & 15;       // A frag-row / B,C col
  const int lg   = lane >> 4;       // k-group / C row-group
  const int sb2  = (lr >> 2) & 1;   // tile-pair member select
  const int sb3  = lr >> 3;         // tile-pair select (ship)
  const int u_bs = lr & 3;          // batch row
  const int u_j  = wid*16 + (2*sb3 + sb2)*4 + lg; // this lane's cell (both layers)
  const int b0   = blockIdx.x * BB;

  // zero h stage (both buffers, both layers): 2048 ints
  {
    int* hz = (int*)hsb;
    #pragma unroll
    for (int i = 0; i < 8; ++i) hz[tid + i*NT] = 0;
  }

  // ---- resident A-fragments (bf16 hi/lo split), gate-interleaved row map ----
  // tile p, frag-row r -> m = (r&3)*64 + wid*16 + p*4 + (r>>2)
  // => C frag reg rg = gate rg of cell (j = wid*16 + p*4 + lg), col lr.
  bf16x8 A0[4][2][2];    // [p][kt][hi/lo]   Whh0
  bf16x8 A1i[4][2][2];   // Wih1
  bf16x8 A1h[4][2][2];   // Whh1
  #pragma unroll
  for (int p = 0; p < 4; ++p){
    const int m = (lr&3)*64 + wid*16 + p*4 + (lr>>2);
    #pragma unroll
    for (int kt = 0; kt < 2; ++kt){
      const int off = m*64 + kt*32 + lg*8;
      float wbuf[8];
      *(float4*)&wbuf[0] = *(const float4*)&Whh0[off];
      *(float4*)&wbuf[4] = *(const float4*)&Whh0[off+4];
      split8(wbuf, A0[p][kt][0], A0[p][kt][1]);
      *(float4*)&wbuf[0] = *(const float4*)&Wih1[off];
      *(float4*)&wbuf[4] = *(const float4*)&Wih1[off+4];
      split8(wbuf, A1i[p][kt][0], A1i[p][kt][1]);
      *(float4*)&wbuf[0] = *(const float4*)&Whh1[off];
      *(float4*)&wbuf[4] = *(const float4*)&Whh1[off+4];
      split8(wbuf, A1h[p][kt][0], A1h[p][kt][1]);
    }
  }

  // update constants: every lane owns cell u_j of BOTH layers (batch u_bs)
  float bias0g[4], bias1g[4], w0r[24];
  #pragma unroll
  for (int gt = 0; gt < 4; ++gt){
    const int row = gt*64 + u_j;
    bias0g[gt] = bih0[row] + bhh0[row];
    bias1g[gt] = bih1[row] + bhh1[row];
    #pragma unroll
    for (int d = 0; d < Dd; ++d) w0r[gt*6+d] = Wih0[row*Dd + d];
  }

  // loop-invariant LDS offsets
  const int boff0 = (lr*128 + lg*16)      ^ ((lr&7)<<4);   // B kt=0 (bytes)
  const int boff1 = (lr*128 + 64 + lg*16) ^ ((lr&7)<<4);   // B kt=1
  const int whi   = (u_bs*128     + u_j*2) ^ (u_bs<<4);    // h_hi write (bytes)
  const int wlo   = ((u_bs+4)*128 + u_j*2) ^ ((u_bs+4)<<4);// h_lo write

  // x stream for this lane's batch row (6 floats/step, float2-aligned)
  const float2* px2 = (const float2*)(x + (size_t)(b0 + u_bs) * (Tt*Dd));
  float2 xi0 = px2[0], xi1 = px2[1], xi2 = px2[2];   // x(0)
  float2 xc0 = px2[3], xc1 = px2[4], xc2 = px2[5];   // x(1)
  float2 xf0 = px2[6], xf1 = px2[7], xf2 = px2[8];   // x(2)

  float c0reg = 0.f, c1reg = 0.f;
  __syncthreads();

  // prologue: h0(0) from x(0) only (h0(-1)=0) — every lane does its L0 cell
  {
    float s[4];
    #pragma unroll
    for (int gt = 0; gt < 4; ++gt)
      s[gt] = bias0g[gt] + w0r[gt*6+0]*xi0.x + w0r[gt*6+1]*xi0.y
            + w0r[gt*6+2]*xi1.x + w0r[gt*6+3]*xi1.y
            + w0r[gt*6+4]*xi2.x + w0r[gt*6+5]*xi2.y;
    float iv = sigm(s[0]), fv = sigm(s[1]), gv = tanh_(s[2]), ov = sigm(s[3]);
    c0reg = fv*c0reg + iv*gv;
    float hval = ov * tanh_(c0reg);
    unsigned short hh = f2bf(hval);
    unsigned short hl = f2bf(hval - bf2f(hh));
    char* hw = (char*)hsb;                 // buf0, layer0 plane
    *(short*)(hw + whi) = (short)hh;
    *(short*)(hw + wlo) = (short)hl;
  }
  __syncthreads();

  // steady state: at iter t, hsb[t&1] holds h0(t) (plane0) and h1(t-1) (plane1)
  #pragma unroll 2
  for (int t = 0; t < Tt; ++t){
    // prefetch x(t+3)
    float2 xn0, xn1, xn2;
    {
      const int tl = (t+3 < Tt) ? (t+3) : (Tt-1);
      xn0 = px2[tl*3]; xn1 = px2[tl*3+1]; xn2 = px2[tl*3+2];
    }

    const int buf = t & 1;
    const char* hb = (const char*)hsb + buf*4096;
    bf16x8 b00 = *(const bf16x8*)(hb + boff0);          // h0 kt0
    bf16x8 b01 = *(const bf16x8*)(hb + boff1);          // h0 kt1
    bf16x8 b10 = *(const bf16x8*)(hb + 2048 + boff0);   // h1 kt0
    bf16x8 b11 = *(const bf16x8*)(hb + 2048 + boff1);   // h1 kt1

    f32x4 a0_[4], a1i_[4], a1h_[4];
    #pragma unroll
    for (int p = 0; p < 4; ++p){
      a0_[p] = (f32x4){0,0,0,0}; a1i_[p] = (f32x4){0,0,0,0}; a1h_[p] = (f32x4){0,0,0,0};
    }
    // 12 independent chains, each 4 deep
    #pragma unroll
    for (int p = 0; p < 4; ++p){
      MF(A0[p][0][0], b00, a0_[p]);
      MF(A0[p][1][0], b01, a0_[p]);
      MF(A0[p][0][1], b00, a0_[p]);
      MF(A0[p][1][1], b01, a0_[p]);
    }
    #pragma unroll
    for (int p = 0; p < 4; ++p){
      MF(A1i[p][0][0], b00, a1i_[p]);
      MF(A1i[p][1][0], b01, a1i_[p]);
      MF(A1i[p][0][1], b00, a1i_[p]);
      MF(A1i[p][1][1], b01, a1i_[p]);
    }
    #pragma unroll
    for (int p = 0; p < 4; ++p){
      MF(A1h[p][0][0], b10, a1h_[p]);
      MF(A1h[p][1][0], b11, a1h_[p]);
      MF(A1h[p][0][1], b10, a1h_[p]);
      MF(A1h[p][1][1], b11, a1h_[p]);
    }

    // gather: lane needs cell u_j = wid*16 + (2*sb3+sb2)*4 + lg, batch col u_bs
    // (hi col + lo col). sb2: own/send trick (xor4); sb3: shipped pair (xor8).
    float g0[4], g1[4];
    #pragma unroll
    for (int rg = 0; rg < 4; ++rg){
      // layer 0
      float own  = sb2 ? a0_[1][rg] : a0_[0][rg];
      float snd  = sb2 ? a0_[0][rg] : a0_[1][rg];
      float own2 = sb2 ? a0_[3][rg] : a0_[2][rg];
      float snd2 = sb2 ? a0_[2][rg] : a0_[3][rg];
      float f  = own  + __shfl_xor(snd, 4);
      float f2 = own2 + __shfl_xor(snd2, 4);
      g0[rg] = sb3 ? __shfl_xor(f2, 8) : f;
      // layer 1 (merge ih+hh chains first)
      float m0 = a1i_[0][rg] + a1h_[0][rg];
      float m1 = a1i_[1][rg] + a1h_[1][rg];
      float m2 = a1i_[2][rg] + a1h_[2][rg];
      float m3 = a1i_[3][rg] + a1h_[3][rg];
      float o1  = sb2 ? m1 : m0, s1_ = sb2 ? m0 : m1;
      float o2_ = sb2 ? m3 : m2, s2_ = sb2 ? m2 : m3;
      float h_  = o1  + __shfl_xor(s1_, 4);
      float h2_ = o2_ + __shfl_xor(s2_, 4);
      g1[rg] = sb3 ? __shfl_xor(h2_, 8) : h_;
    }

    // ---- L0 update: h0(t+1) ----
    if (t+1 < Tt){
      float s0 = g0[0] + bias0g[0]
               + w0r[ 0]*xc0.x + w0r[ 1]*xc0.y + w0r[ 2]*xc1.x
               + w0r[ 3]*xc1.y + w0r[ 4]*xc2.x + w0r[ 5]*xc2.y;
      float s1 = g0[1] + bias0g[1]
               + w0r[ 6]*xc0.x + w0r[ 7]*xc0.y + w0r[ 8]*xc1.x
               + w0r[ 9]*xc1.y + w0r[10]*xc2.x + w0r[11]*xc2.y;
      float s2 = g0[2] + bias0g[2]
               + w0r[12]*xc0.x + w0r[13]*xc0.y + w0r[14]*xc1.x
               + w0r[15]*xc1.y + w0r[16]*xc2.x + w0r[17]*xc2.y;
      float s3 = g0[3] + bias0g[3]
               + w0r[18]*xc0.x + w0r[19]*xc0.y + w0r[20]*xc1.x
               + w0r[21]*xc1.y + w0r[22]*xc2.x + w0r[23]*xc2.y;
      float iv = sigm(s0), fv = sigm(s1), gv = tanh_(s2), ov = sigm(s3);
      c0reg = fv*c0reg + iv*gv;
      float hval = ov * tanh_(c0reg);
      unsigned short hh = f2bf(hval);
      unsigned short hl = f2bf(hval - bf2f(hh));
      char* hw = (char*)hsb + (buf^1)*4096;          // plane 0
      *(short*)(hw + whi) = (short)hh;
      *(short*)(hw + wlo) = (short)hl;
    }

    // ---- L1 update: h1(t) ----
    {
      float s0 = g1[0] + bias1g[0];
      float s1 = g1[1] + bias1g[1];
      float s2 = g1[2] + bias1g[2];
      float s3 = g1[3] + bias1g[3];
      float iv = sigm(s0), fv = sigm(s1), gv = tanh_(s2), ov = sigm(s3);
      c1reg = fv*c1reg + iv*gv;
      float hval = ov * tanh_(c1reg);
      if (t == Tt-1) h1f[u_bs*64 + u_j] = hval;
      unsigned short hh = f2bf(hval);
      unsigned short hl = f2bf(hval - bf2f(hh));
      char* hw = (char*)hsb + (buf^1)*4096 + 2048;   // plane 1
      *(short*)(hw + whi) = (short)hh;
      *(short*)(hw + wlo) = (short)hl;
    }

    // rotate x pipeline
    xc0 = xf0; xc1 = xf1; xc2 = xf2;
    xf0 = xn0; xf1 = xn1; xf2 = xn2;

    __syncthreads();   // the ONE barrier per step (h double-buffered)
  }

  // ---- MLP head on h1(T-1) ----
  if (tid < BB*32){
    const int bsh = tid >> 5, m = tid & 31;
    float acc = b1[m];
    #pragma unroll
    for (int j = 0; j < Hh; ++j) acc += W1[m*Hh + j] * h1f[bsh*64 + j];
    zs[bsh*32 + m] = fmaxf(acc, 0.f);
  }
  __syncthreads();
  if (tid < BB){
    float acc = b2[0];
    #pragma unroll
    for (int m = 0; m < 32; ++m) acc += W2[m] * zs[tid*32 + m];
    out[b0 + tid] = sigm(acc);
  }
}

extern "C" void kernel_launch(void* const* d_in, const int* in_sizes, int n_in,
                              void* d_out, int out_size, void* d_ws, size_t ws_size,
                              hipStream_t stream) {
  const float* x    = (const float*)d_in[0];
  const float* Wih0 = (const float*)d_in[1];
  const float* Whh0 = (const float*)d_in[2];
  const float* bih0 = (const float*)d_in[3];
  const float* bhh0 = (const float*)d_in[4];
  const float* Wih1 = (const float*)d_in[5];
  const float* Whh1 = (const float*)d_in[6];
  const float* bih1 = (const float*)d_in[7];
  const float* bhh1 = (const float*)d_in[8];
  const float* W1   = (const float*)d_in[9];
  const float* b1   = (const float*)d_in[10];
  const float* W2   = (const float*)d_in[11];
  const float* b2   = (const float*)d_in[12];

  const int B = in_sizes[0] / (Tt*Dd);   // 1024
  dim3 grid(B / BB), block(NT);
  hipLaunchKernelGGL(lstm2_mfma, grid, block, 0, stream,
                     x, Wih0, Whh0, bih0, bhh0, Wih1, Whh1, bih1, bhh1,
                     W1, b1, W2, b2, (float*)d_out);
}

// Round 9
// 577.508 us; speedup vs baseline: 1.3333x; 1.3333x over previous
//
#include <hip/hip_runtime.h>
#include <cstdint>

#define Hh 64
#define Tt 512
#define Dd 6
#define BB 8      // batch rows per block (all 16 B-cols: 8 hi + 8 lo)
#define NT 1024   // 16 waves = 4 waves/SIMD

typedef short bf16x8 __attribute__((ext_vector_type(8)));
typedef float f32x4  __attribute__((ext_vector_type(4)));

#define MF(A, B, C) C = __builtin_amdgcn_mfma_f32_16x16x32_bf16(A, B, C, 0, 0, 0)

__device__ __forceinline__ float sigm(float v){
  return __builtin_amdgcn_rcpf(1.f + __expf(-v));
}
__device__ __forceinline__ float tanh_(float v){
  return 1.f - 2.f*__builtin_amdgcn_rcpf(1.f + __expf(2.f*v));
}
__device__ __forceinline__ unsigned short f2bf(float f){
  union { float f; unsigned u; } v; v.f = f;
  unsigned r = v.u + 0x7FFFu + ((v.u >> 16) & 1u);   // RNE
  return (unsigned short)(r >> 16);
}
__device__ __forceinline__ float bf2f(unsigned short b){
  union { unsigned u; float f; } v; v.u = ((unsigned)b) << 16;
  return v.f;
}
__device__ __forceinline__ void split8(const float* w, bf16x8& hi, bf16x8& lo){
  #pragma unroll
  for (int i = 0; i < 8; ++i){
    unsigned short h_ = f2bf(w[i]);
    hi[i] = (short)h_;
    lo[i] = (short)f2bf(w[i] - bf2f(h_));
  }
}

// h stage: hsb[buf][layer] planes [16 n][64 j] bf16, byte ^= (n&7)<<4 swizzle.
// Plane rows 0-7 = h_hi(batch 0-7), rows 8-15 = h_lo(batch 0-7).
__global__ __launch_bounds__(NT, 1)
void lstm2_mfma(const float* __restrict__ x,
                const float* __restrict__ Wih0, const float* __restrict__ Whh0,
                const float* __restrict__ bih0, const float* __restrict__ bhh0,
                const float* __restrict__ Wih1, const float* __restrict__ Whh1,
                const float* __restrict__ bih1, const float* __restrict__ bhh1,
                const float* __restrict__ W1, const float* __restrict__ b1,
                const float* __restrict__ W2, const float* __restrict__ b2,
                float* __restrict__ out)
{
  __shared__ __align__(16) short hsb[2*2*1024];   // 8 KB [buf][layer][16][64]
  __shared__ __align__(16) float h1f[BB*Hh];      // 2 KB
  __shared__ float zs[BB*32];

  const int tid  = threadIdx.x;
  const int lane = tid & 63;
  const int wid  = tid >> 6;        // wave 0..15 — owns M-tile wid
  const int lr   = lane & 15;       // A frag-row / B,C col
  const int lg   = lane >> 4;       // k-group / C row-group / update jloc
  const int u_l  = (lane >> 3) & 1; // update: layer (col bit 3 = hi/lo half)
  const int u_bs = lane & 7;        // update: batch row
  const int u_j  = wid*4 + lg;      // update: hidden index
  const int b0   = blockIdx.x * BB;

  // zero h stage (both buffers, both layers): 4096 ints / 1024 threads
  {
    int* hz = (int*)hsb;
    #pragma unroll
    for (int i = 0; i < 4; ++i) hz[tid + i*NT] = 0;
  }

  // ---- resident A-fragments (bf16 hi/lo split), gate-interleaved row map ----
  // frag-row r -> m = (r&3)*64 + wid*4 + (r>>2)
  // => C frag reg rg = gate rg of cell (j = wid*4 + lg_c), col = batch (&7), hi/lo (bit3).
  bf16x8 A0[2][2];    // [kt][hi/lo]  Whh0
  bf16x8 A1i[2][2];   // Wih1
  bf16x8 A1h[2][2];   // Whh1
  {
    const int m = (lr&3)*64 + wid*4 + (lr>>2);
    #pragma unroll
    for (int kt = 0; kt < 2; ++kt){
      const int off = m*64 + kt*32 + lg*8;
      float wbuf[8];
      *(float4*)&wbuf[0] = *(const float4*)&Whh0[off];
      *(float4*)&wbuf[4] = *(const float4*)&Whh0[off+4];
      split8(wbuf, A0[kt][0], A0[kt][1]);
      *(float4*)&wbuf[0] = *(const float4*)&Wih1[off];
      *(float4*)&wbuf[4] = *(const float4*)&Wih1[off+4];
      split8(wbuf, A1i[kt][0], A1i[kt][1]);
      *(float4*)&wbuf[0] = *(const float4*)&Whh1[off];
      *(float4*)&wbuf[4] = *(const float4*)&Whh1[off+4];
      split8(wbuf, A1h[kt][0], A1h[kt][1]);
    }
  }

  // update constants: lane owns cell (u_l, u_bs, u_j). x-proj split across the
  // (lane, lane^8) pair: this lane computes Wih0 gates {2*u_l, 2*u_l+1} of the
  // PAIR's L0 cell (same u_j, u_bs).
  float bias_g[4], w0r[12];
  #pragma unroll
  for (int gt = 0; gt < 4; ++gt){
    const int row = gt*64 + u_j;
    bias_g[gt] = (u_l == 0) ? (bih0[row] + bhh0[row]) : (bih1[row] + bhh1[row]);
  }
  #pragma unroll
  for (int e = 0; e < 2; ++e){
    const int row = (2*u_l + e)*64 + u_j;
    #pragma unroll
    for (int d = 0; d < Dd; ++d) w0r[e*6+d] = Wih0[row*Dd + d];
  }

  // loop-invariant LDS offsets
  const int boff0 = (lr*128 + lg*16)      ^ ((lr&7)<<4);   // B kt=0 (bytes)
  const int boff1 = (lr*128 + 64 + lg*16) ^ ((lr&7)<<4);   // B kt=1
  const int whi   = (u_bs*128     + u_j*2) ^ (u_bs<<4);    // h_hi write (bytes)
  const int wlo   = ((u_bs+8)*128 + u_j*2) ^ (u_bs<<4);    // h_lo write ((u_bs+8)&7==u_bs)

  // x stream for this lane's batch row (6 floats/step, float2-aligned)
  const float2* px2 = (const float2*)(x + (size_t)(b0 + u_bs) * (Tt*Dd));
  float2 xc0 = px2[3], xc1 = px2[4], xc2 = px2[5];   // x(1)
  float2 xf0 = px2[6], xf1 = px2[7], xf2 = px2[8];   // x(2)

  float creg = 0.f;
  __syncthreads();

  // prologue: h0(0) from x(0) only (h0(-1)=0)
  {
    float2 xi0 = px2[0], xi1 = px2[1], xi2 = px2[2];
    float xpA = w0r[0]*xi0.x + w0r[1]*xi0.y + w0r[2]*xi1.x
              + w0r[3]*xi1.y + w0r[4]*xi2.x + w0r[5]*xi2.y;
    float xpB = w0r[6]*xi0.x + w0r[7]*xi0.y + w0r[8]*xi1.x
              + w0r[9]*xi1.y + w0r[10]*xi2.x + w0r[11]*xi2.y;
    float r2 = __shfl_xor(xpA, 8), r3 = __shfl_xor(xpB, 8);
    if (u_l == 0){
      float s0 = bias_g[0] + xpA, s1 = bias_g[1] + xpB;
      float s2 = bias_g[2] + r2,  s3 = bias_g[3] + r3;
      float iv = sigm(s0), fv = sigm(s1), gv = tanh_(s2), ov = sigm(s3);
      creg = fv*creg + iv*gv;
      float hval = ov * tanh_(creg);
      unsigned short hh = f2bf(hval);
      unsigned short hl = f2bf(hval - bf2f(hh));
      char* hw = (char*)hsb;                 // buf0, plane 0
      *(short*)(hw + whi) = (short)hh;
      *(short*)(hw + wlo) = (short)hl;
    }
  }
  __syncthreads();

  // steady state: at iter t, hsb[t&1] holds h0(t) (plane0) and h1(t-1) (plane1)
  #pragma unroll 2
  for (int t = 0; t < Tt; ++t){
    // prefetch x(t+3)
    float2 xn0, xn1, xn2;
    {
      const int tl = (t+3 < Tt) ? (t+3) : (Tt-1);
      xn0 = px2[tl*3]; xn1 = px2[tl*3+1]; xn2 = px2[tl*3+2];
    }

    const int buf = t & 1;
    const char* hb = (const char*)hsb + buf*4096;
    bf16x8 b00 = *(const bf16x8*)(hb + boff0);          // h0 kt0
    bf16x8 b01 = *(const bf16x8*)(hb + boff1);          // h0 kt1
    bf16x8 b10 = *(const bf16x8*)(hb + 2048 + boff0);   // h1 kt0
    bf16x8 b11 = *(const bf16x8*)(hb + 2048 + boff1);   // h1 kt1

    f32x4 a0 = {0,0,0,0}, a1i = {0,0,0,0}, a1h = {0,0,0,0};
    // 3 independent 4-deep chains; cols 0-7 get W*h_hi, cols 8-15 get W*h_lo,
    // hi+lo A-frags accumulate into the same C => all 4 split terms present.
    MF(A0[0][0], b00, a0);  MF(A1i[0][0], b00, a1i);  MF(A1h[0][0], b10, a1h);
    MF(A0[1][0], b01, a0);  MF(A1i[1][0], b01, a1i);  MF(A1h[1][0], b11, a1h);
    MF(A0[0][1], b00, a0);  MF(A1i[0][1], b00, a1i);  MF(A1h[0][1], b10, a1h);
    MF(A0[1][1], b01, a0);  MF(A1i[1][1], b01, a1i);  MF(A1h[1][1], b11, a1h);

    // x-projection for the pair's L0 cell (2 gates here, 2 at partner)
    float xpA = w0r[0]*xc0.x + w0r[1]*xc0.y + w0r[2]*xc1.x
              + w0r[3]*xc1.y + w0r[4]*xc2.x + w0r[5]*xc2.y;
    float xpB = w0r[6]*xc0.x + w0r[7]*xc0.y + w0r[8]*xc1.x
              + w0r[9]*xc1.y + w0r[10]*xc2.x + w0r[11]*xc2.y;
    float r2 = __shfl_xor(xpA, 8), r3 = __shfl_xor(xpB, 8);

    // gather: pair (lane, lane^8) holds hi/lo cols of the same cell
    float s0, s1, s2, s3;
    {
      float m0 = a1i[0] + a1h[0], m1 = a1i[1] + a1h[1],
            m2 = a1i[2] + a1h[2], m3 = a1i[3] + a1h[3];
      float q0 = u_l ? m0 : a0[0], q1 = u_l ? m1 : a0[1],
            q2 = u_l ? m2 : a0[2], q3 = u_l ? m3 : a0[3];
      // need hi+lo col sum for OWN layer: own value + partner's value
      s0 = q0 + __shfl_xor(u_l ? m0 : a0[0], 8);
      s1 = q1 + __shfl_xor(u_l ? m1 : a0[1], 8);
      s2 = q2 + __shfl_xor(u_l ? m2 : a0[2], 8);
      s3 = q3 + __shfl_xor(u_l ? m3 : a0[3], 8);
    }
    s0 += bias_g[0]; s1 += bias_g[1]; s2 += bias_g[2]; s3 += bias_g[3];
    if (u_l == 0){ s0 += xpA; s1 += xpB; s2 += r2; s3 += r3; }

    // ---- update (one cell per lane) ----
    if ((u_l == 1) | (t+1 < Tt)){
      float iv = sigm(s0), fv = sigm(s1), gv = tanh_(s2), ov = sigm(s3);
      creg = fv*creg + iv*gv;
      float hval = ov * tanh_(creg);
      if ((u_l == 1) & (t == Tt-1)) h1f[u_bs*64 + u_j] = hval;
      unsigned short hh = f2bf(hval);
      unsigned short hl = f2bf(hval - bf2f(hh));
      char* hw = (char*)hsb + (buf^1)*4096 + u_l*2048;
      *(short*)(hw + whi) = (short)hh;
      *(short*)(hw + wlo) = (short)hl;
    }

    // rotate x pipeline
    xc0 = xf0; xc1 = xf1; xc2 = xf2;
    xf0 = xn0; xf1 = xn1; xf2 = xn2;

    __syncthreads();   // the ONE barrier per step (h double-buffered)
  }

  // ---- MLP head on h1(T-1) ----
  if (tid < BB*32){
    const int bsh = tid >> 5, m = tid & 31;
    float acc = b1[m];
    #pragma unroll
    for (int j = 0; j < Hh; ++j) acc += W1[m*Hh + j] * h1f[bsh*64 + j];
    zs[bsh*32 + m] = fmaxf(acc, 0.f);
  }
  __syncthreads();
  if (tid < BB){
    float acc = b2[0];
    #pragma unroll
    for (int m = 0; m < 32; ++m) acc += W2[m] * zs[tid*32 + m];
    out[b0 + tid] = sigm(acc);
  }
}

extern "C" void kernel_launch(void* const* d_in, const int* in_sizes, int n_in,
                              void* d_out, int out_size, void* d_ws, size_t ws_size,
                              hipStream_t stream) {
  const float* x    = (const float*)d_in[0];
  const float* Wih0 = (const float*)d_in[1];
  const float* Whh0 = (const float*)d_in[2];
  const float* bih0 = (const float*)d_in[3];
  const float* bhh0 = (const float*)d_in[4];
  const float* Wih1 = (const float*)d_in[5];
  const float* Whh1 = (const float*)d_in[6];
  const float* bih1 = (const float*)d_in[7];
  const float* bhh1 = (const float*)d_in[8];
  const float* W1   = (const float*)d_in[9];
  const float* b1   = (const float*)d_in[10];
  const float* W2   = (const float*)d_in[11];
  const float* b2   = (const float*)d_in[12];

  const int B = in_sizes[0] / (Tt*Dd);   // 1024
  dim3 grid(B / BB), block(NT);
  hipLaunchKernelGGL(lstm2_mfma, grid, block, 0, stream,
                     x, Wih0, Whh0, bih0, bhh0, Wih1, Whh1, bih1, bhh1,
                     W1, b1, W2, b2, (float*)d_out);
}

// Round 10
// 540.033 us; speedup vs baseline: 1.4259x; 1.0694x over previous
//
#include <hip/hip_runtime.h>
#include <cstdint>

#define Hh 64
#define Tt 512
#define Dd 6
#define BB 4      // batch rows per block
#define NT 512    // 8 waves, grid=256 -> 1 block/CU, 2 waves/SIMD

typedef short bf16x8 __attribute__((ext_vector_type(8)));
typedef float f32x4  __attribute__((ext_vector_type(4)));

#define MF(A, B, C) C = __builtin_amdgcn_mfma_f32_16x16x32_bf16(A, B, C, 0, 0, 0)

__device__ __forceinline__ float sigm(float v){
  return __builtin_amdgcn_rcpf(1.f + __expf(-v));
}
__device__ __forceinline__ float tanh_(float v){
  return 1.f - 2.f*__builtin_amdgcn_rcpf(1.f + __expf(2.f*v));
}
__device__ __forceinline__ unsigned short f2bf(float f){
  union { float f; unsigned u; } v; v.f = f;
  unsigned r = v.u + 0x7FFFu + ((v.u >> 16) & 1u);   // RNE
  return (unsigned short)(r >> 16);
}
__device__ __forceinline__ float bf2f(unsigned short b){
  union { unsigned u; float f; } v; v.u = ((unsigned)b) << 16;
  return v.f;
}
__device__ __forceinline__ void split8(const float* w, bf16x8& hi, bf16x8& lo){
  #pragma unroll
  for (int i = 0; i < 8; ++i){
    unsigned short h_ = f2bf(w[i]);
    hi[i] = (short)h_;
    lo[i] = (short)f2bf(w[i] - bf2f(h_));
  }
}
// fast trunc-based hi/lo split of h (residual captured exactly by lo)
__device__ __forceinline__ void splitH(float v, unsigned short& hh, unsigned short& hl){
  union { float f; unsigned u; } a; a.f = v;
  hh = (unsigned short)(a.u >> 16);            // trunc toward zero
  float resid = v - bf2f(hh);                  // |resid| < 2^-8 * |v|
  union { float f; unsigned u; } b; b.f = resid;
  hl = (unsigned short)(b.u >> 16);            // trunc again (lo of lo ~2^-17)
}

// h stage: hsb[buf][layer] planes [16 n][64 j] bf16, byte ^= (n&7)<<4 swizzle.
// Rows 0-3 = h_hi(bs), 4-7 = h_lo(bs), 8-15 zero.
__global__ __launch_bounds__(NT, 1)
void lstm2_mfma(const float* __restrict__ x,
                const float* __restrict__ Wih0, const float* __restrict__ Whh0,
                const float* __restrict__ bih0, const float* __restrict__ bhh0,
                const float* __restrict__ Wih1, const float* __restrict__ Whh1,
                const float* __restrict__ bih1, const float* __restrict__ bhh1,
                const float* __restrict__ W1, const float* __restrict__ b1,
                const float* __restrict__ W2, const float* __restrict__ b2,
                float* __restrict__ out)
{
  __shared__ __align__(16) short hsb[2*2*1024];   // 8 KB [buf][layer][16][64]
  __shared__ __align__(16) float h1f[BB*Hh];
  __shared__ float zs[BB*32];

  const int tid  = threadIdx.x;
  const int lane = tid & 63;
  const int wid  = tid >> 6;        // wave 0..7
  const int lr   = lane & 15;       // A frag-row / B,C col
  const int lg   = lane >> 4;       // k-group / C row-group
  const int b0   = blockIdx.x * BB;

  // update mapping: every lane owns exactly one cell
  const int u_l  = lr >> 3;         // layer
  const int u_p  = (lr >> 2) & 1;   // tile (j sub-block)
  const int u_bs = lr & 3;          // batch row
  const int u_j  = wid*8 + u_p*4 + lg;

  // zero h stage (both buffers, both layers)
  {
    int* hz = (int*)hsb;
    hz[tid] = 0; hz[tid+NT] = 0; hz[tid+2*NT] = 0; hz[tid+3*NT] = 0;
  }

  // ---- resident A-fragments (bf16 hi/lo split), gate-interleaved row map ----
  // tile p, frag-row r -> m = (r&3)*64 + wid*8 + p*4 + (r>>2)
  // => C frag reg rg = gate rg of cell (j = wid*8 + p*4 + lg), col lr.
  bf16x8 A0[2][2][2];       // [p][kt][hi/lo]            Whh0
  bf16x8 A1[2][2][2][2];    // [p][mat ih/hh][kt][hi/lo]
  #pragma unroll
  for (int p = 0; p < 2; ++p){
    const int m = (lr&3)*64 + wid*8 + p*4 + (lr>>2);
    #pragma unroll
    for (int kt = 0; kt < 2; ++kt){
      const int off = m*64 + kt*32 + lg*8;
      float wbuf[8];
      *(float4*)&wbuf[0] = *(const float4*)&Whh0[off];
      *(float4*)&wbuf[4] = *(const float4*)&Whh0[off+4];
      split8(wbuf, A0[p][kt][0], A0[p][kt][1]);
      *(float4*)&wbuf[0] = *(const float4*)&Wih1[off];
      *(float4*)&wbuf[4] = *(const float4*)&Wih1[off+4];
      split8(wbuf, A1[p][0][kt][0], A1[p][0][kt][1]);
      *(float4*)&wbuf[0] = *(const float4*)&Whh1[off];
      *(float4*)&wbuf[4] = *(const float4*)&Whh1[off+4];
      split8(wbuf, A1[p][1][kt][0], A1[p][1][kt][1]);
    }
  }

  // update-phase constants (cell = (u_l, u_bs, u_j))
  float bias_g[4], w0r[24];
  #pragma unroll
  for (int gt = 0; gt < 4; ++gt){
    const int row = gt*64 + u_j;
    if (u_l == 0){
      bias_g[gt] = bih0[row] + bhh0[row];
      #pragma unroll
      for (int d = 0; d < Dd; ++d) w0r[gt*6+d] = Wih0[row*Dd + d];
    } else {
      bias_g[gt] = bih1[row] + bhh1[row];
      #pragma unroll
      for (int d = 0; d < Dd; ++d) w0r[gt*6+d] = 0.f;
    }
  }

  // loop-invariant LDS offsets
  const int boff0 = (lr*128 + lg*16)      ^ ((lr&7)<<4);   // B kt=0 (bytes)
  const int boff1 = (lr*128 + 64 + lg*16) ^ ((lr&7)<<4);   // B kt=1
  const int whi   = (u_bs*128     + u_j*2) ^ (u_bs<<4);    // h_hi write (bytes)
  const int wlo   = ((u_bs+4)*128 + u_j*2) ^ ((u_bs+4)<<4);// h_lo write

  // x stream for this lane's batch row (6 floats/step, float2-aligned)
  const float2* px2 = (const float2*)(x + (size_t)(b0 + u_bs) * (Tt*Dd));
  float2 xi0 = px2[0], xi1 = px2[1], xi2 = px2[2];   // x(0)
  float2 xc0 = px2[3], xc1 = px2[4], xc2 = px2[5];   // x(1)
  float2 xf0 = px2[6], xf1 = px2[7], xf2 = px2[8];   // x(2)

  float creg = 0.f;
  __syncthreads();

  // prologue: h0(0) from x(0) only (h0(-1)=0), layer-0 lanes
  if (u_l == 0){
    float s[4];
    #pragma unroll
    for (int gt = 0; gt < 4; ++gt)
      s[gt] = bias_g[gt] + w0r[gt*6+0]*xi0.x + w0r[gt*6+1]*xi0.y
            + w0r[gt*6+2]*xi1.x + w0r[gt*6+3]*xi1.y
            + w0r[gt*6+4]*xi2.x + w0r[gt*6+5]*xi2.y;
    float iv = sigm(s[0]), fv = sigm(s[1]), gv = tanh_(s[2]), ov = sigm(s[3]);
    creg = fv*creg + iv*gv;
    float hval = ov * tanh_(creg);
    unsigned short hh, hl; splitH(hval, hh, hl);
    char* hw = (char*)hsb;                 // buf0, layer0 plane
    *(short*)(hw + whi) = (short)hh;
    *(short*)(hw + wlo) = (short)hl;
  }
  __syncthreads();

  // steady state: at iter t, hsb[t&1] holds h0(t) (plane0) and h1(t-1) (plane1)
  #pragma unroll 2
  for (int t = 0; t < Tt; ++t){
    // prefetch x(t+3) — stays in flight across the (lgkm-only) barrier
    float2 xn0, xn1, xn2;
    {
      const int tl = (t+3 < Tt) ? (t+3) : (Tt-1);
      xn0 = px2[tl*3]; xn1 = px2[tl*3+1]; xn2 = px2[tl*3+2];
    }

    const int buf = t & 1;
    const char* hb = (const char*)hsb + buf*4096;
    bf16x8 b00 = *(const bf16x8*)(hb + boff0);          // h0 kt0
    bf16x8 b01 = *(const bf16x8*)(hb + boff1);          // h0 kt1
    bf16x8 b10 = *(const bf16x8*)(hb + 2048 + boff0);   // h1 kt0
    bf16x8 b11 = *(const bf16x8*)(hb + 2048 + boff1);   // h1 kt1

    f32x4 a00  = {0,0,0,0}, a01  = {0,0,0,0};
    f32x4 a1iA = {0,0,0,0}, a1iB = {0,0,0,0};
    f32x4 a1hA = {0,0,0,0}, a1hB = {0,0,0,0};

    // L0 first (its consumers run earliest), all chains <= 4 deep
    MF(A0[0][0][0], b00, a00); MF(A0[1][0][0], b00, a01);
    MF(A0[0][1][0], b01, a00); MF(A0[1][1][0], b01, a01);
    MF(A0[0][0][1], b00, a00); MF(A0[1][0][1], b00, a01);
    MF(A0[0][1][1], b01, a00); MF(A0[1][1][1], b01, a01);
    // L1 ih / hh as separate 4-deep chains
    MF(A1[0][0][0][0], b00, a1iA); MF(A1[1][0][0][0], b00, a1iB);
    MF(A1[0][0][1][0], b01, a1iA); MF(A1[1][0][1][0], b01, a1iB);
    MF(A1[0][0][0][1], b00, a1iA); MF(A1[1][0][0][1], b00, a1iB);
    MF(A1[0][0][1][1], b01, a1iA); MF(A1[1][0][1][1], b01, a1iB);
    MF(A1[0][1][0][0], b10, a1hA); MF(A1[1][1][0][0], b10, a1hB);
    MF(A1[0][1][1][0], b11, a1hA); MF(A1[1][1][1][0], b11, a1hB);
    MF(A1[0][1][0][1], b10, a1hA); MF(A1[1][1][0][1], b10, a1hB);
    MF(A1[0][1][1][1], b11, a1hA); MF(A1[1][1][1][1], b11, a1hB);

    // ---- L0 gather + update + write (overlaps L1 MFMA drain) ----
    float g0[4];
    #pragma unroll
    for (int rg = 0; rg < 4; ++rg){
      float own = (lr & 4) ? a01[rg] : a00[rg];
      float snd = (lr & 4) ? a00[rg] : a01[rg];
      g0[rg] = own + __shfl_xor(snd, 4);
    }
    if ((u_l == 0) & (t+1 < Tt)){
      float s0 = g0[0] + bias_g[0]
               + w0r[ 0]*xc0.x + w0r[ 1]*xc0.y + w0r[ 2]*xc1.x
               + w0r[ 3]*xc1.y + w0r[ 4]*xc2.x + w0r[ 5]*xc2.y;
      float s1 = g0[1] + bias_g[1]
               + w0r[ 6]*xc0.x + w0r[ 7]*xc0.y + w0r[ 8]*xc1.x
               + w0r[ 9]*xc1.y + w0r[10]*xc2.x + w0r[11]*xc2.y;
      float s2 = g0[2] + bias_g[2]
               + w0r[12]*xc0.x + w0r[13]*xc0.y + w0r[14]*xc1.x
               + w0r[15]*xc1.y + w0r[16]*xc2.x + w0r[17]*xc2.y;
      float s3 = g0[3] + bias_g[3]
               + w0r[18]*xc0.x + w0r[19]*xc0.y + w0r[20]*xc1.x
               + w0r[21]*xc1.y + w0r[22]*xc2.x + w0r[23]*xc2.y;
      float iv = sigm(s0), fv = sigm(s1), gv = tanh_(s2), ov = sigm(s3);
      creg = fv*creg + iv*gv;
      float hval = ov * tanh_(creg);
      unsigned short hh, hl; splitH(hval, hh, hl);
      char* hw = (char*)hsb + (buf^1)*4096;            // plane 0
      *(short*)(hw + whi) = (short)hh;
      *(short*)(hw + wlo) = (short)hl;
    }

    // ---- L1 gather + update + write ----
    float g1[4];
    #pragma unroll
    for (int rg = 0; rg < 4; ++rg){
      float m0 = a1iA[rg] + a1hA[rg];
      float m1 = a1iB[rg] + a1hB[rg];
      float s10 = m0 + __shfl_xor(m0, 4);
      float s11 = m1 + __shfl_xor(m1, 4);
      float snd = (lr & 4) ? s11 : s10;
      g1[rg] = __shfl_xor(snd, 8);
    }
    if (u_l == 1){
      float s0 = g1[0] + bias_g[0];
      float s1 = g1[1] + bias_g[1];
      float s2 = g1[2] + bias_g[2];
      float s3 = g1[3] + bias_g[3];
      float iv = sigm(s0), fv = sigm(s1), gv = tanh_(s2), ov = sigm(s3);
      creg = fv*creg + iv*gv;
      float hval = ov * tanh_(creg);
      if (t == Tt-1) h1f[u_bs*64 + u_j] = hval;
      unsigned short hh, hl; splitH(hval, hh, hl);
      char* hw = (char*)hsb + (buf^1)*4096 + 2048;     // plane 1
      *(short*)(hw + whi) = (short)hh;
      *(short*)(hw + wlo) = (short)hl;
    }

    // rotate x pipeline
    xc0 = xf0; xc1 = xf1; xc2 = xf2;
    xf0 = xn0; xf1 = xn1; xf2 = xn2;

    // lgkm-only barrier: LDS writes drained, global x-prefetch stays in flight
    asm volatile("s_waitcnt lgkmcnt(0)\n\ts_barrier" ::: "memory");
  }

  __syncthreads();

  // ---- MLP head on h1(T-1) ----
  if (tid < BB*32){
    const int bsh = tid >> 5, m = tid & 31;
    float acc = b1[m];
    #pragma unroll
    for (int j = 0; j < Hh; ++j) acc += W1[m*Hh + j] * h1f[bsh*64 + j];
    zs[bsh*32 + m] = fmaxf(acc, 0.f);
  }
  __syncthreads();
  if (tid < BB){
    float acc = b2[0];
    #pragma unroll
    for (int m = 0; m < 32; ++m) acc += W2[m] * zs[tid*32 + m];
    out[b0 + tid] = sigm(acc);
  }
}

extern "C" void kernel_launch(void* const* d_in, const int* in_sizes, int n_in,
                              void* d_out, int out_size, void* d_ws, size_t ws_size,
                              hipStream_t stream) {
  const float* x    = (const float*)d_in[0];
  const float* Wih0 = (const float*)d_in[1];
  const float* Whh0 = (const float*)d_in[2];
  const float* bih0 = (const float*)d_in[3];
  const float* bhh0 = (const float*)d_in[4];
  const float* Wih1 = (const float*)d_in[5];
  const float* Whh1 = (const float*)d_in[6];
  const float* bih1 = (const float*)d_in[7];
  const float* bhh1 = (const float*)d_in[8];
  const float* W1   = (const float*)d_in[9];
  const float* b1   = (const float*)d_in[10];
  const float* W2   = (const float*)d_in[11];
  const float* b2   = (const float*)d_in[12];

  const int B = in_sizes[0] / (Tt*Dd);   // 1024
  dim3 grid(B / BB), block(NT);
  hipLaunchKernelGGL(lstm2_mfma, grid, block, 0, stream,
                     x, Wih0, Whh0, bih0, bhh0, Wih1, Whh1, bih1, bhh1,
                     W1, b1, W2, b2, (float*)d_out);
}

// Round 11
// 430.603 us; speedup vs baseline: 1.7882x; 1.2541x over previous
//
#include <hip/hip_runtime.h>
#include <cstdint>

#define Hh 64
#define Tt 512
#define Dd 6
#define BB 4
#define NT 512    // 8 waves: 0-3 = L0 engine, 4-7 = L1 engine

typedef short bf16x8 __attribute__((ext_vector_type(8)));
typedef float f32x4  __attribute__((ext_vector_type(4)));

#define MF(A,B,C) C = __builtin_amdgcn_mfma_f32_16x16x32_bf16(A,B,C,0,0,0)

__device__ __forceinline__ float sigm(float v){
  return __builtin_amdgcn_rcpf(1.f + __expf(-v));
}
__device__ __forceinline__ float tanh_(float v){
  return 1.f - 2.f*__builtin_amdgcn_rcpf(1.f + __expf(2.f*v));
}
__device__ __forceinline__ unsigned short f2bf(float f){
  union { float f; unsigned u; } v; v.f = f;
  unsigned r = v.u + 0x7FFFu + ((v.u >> 16) & 1u);
  return (unsigned short)(r >> 16);
}
__device__ __forceinline__ float bf2f(unsigned short b){
  union { unsigned u; float f; } v; v.u = ((unsigned)b) << 16;
  return v.f;
}
__device__ __forceinline__ void split8(const float* w, bf16x8& hi, bf16x8& lo){
  #pragma unroll
  for (int i = 0; i < 8; ++i){
    unsigned short h_ = f2bf(w[i]);
    hi[i] = (short)h_;
    lo[i] = (short)f2bf(w[i] - bf2f(h_));
  }
}
__device__ __forceinline__ void splitH(float v, unsigned short& hh, unsigned short& hl){
  union { float f; unsigned u; } a; a.f = v;
  hh = (unsigned short)(a.u >> 16);
  float r = v - bf2f(hh);
  union { float f; unsigned u; } b; b.f = r;
  hl = (unsigned short)(b.u >> 16);
}
__device__ __forceinline__ void spinGE(int* f, int target){
  while (__hip_atomic_load(f, __ATOMIC_ACQUIRE, __HIP_MEMORY_SCOPE_WORKGROUP) < target)
    __builtin_amdgcn_s_sleep(1);
}
__device__ __forceinline__ void incFlag(int* f, int lane){
  asm volatile("s_waitcnt lgkmcnt(0)" ::: "memory");
  if (lane == 0)
    __hip_atomic_fetch_add(f, 1, __ATOMIC_RELEASE, __HIP_MEMORY_SCOPE_WORKGROUP);
}

// h planes: [16 n][64 j] bf16, byte ^= (n&7)<<4 swizzle. Rows 0-3 = h_hi(bs),
// 4-7 = h_lo(bs), 8-15 zero. h0: 4-slot ring. h1: 2-buf, private to L1 waves.
__global__ __launch_bounds__(NT, 1)
void lstm2_ps(const float* __restrict__ x,
              const float* __restrict__ Wih0, const float* __restrict__ Whh0,
              const float* __restrict__ bih0, const float* __restrict__ bhh0,
              const float* __restrict__ Wih1, const float* __restrict__ Whh1,
              const float* __restrict__ bih1, const float* __restrict__ bhh1,
              const float* __restrict__ W1, const float* __restrict__ b1,
              const float* __restrict__ W2, const float* __restrict__ b2,
              float* __restrict__ out)
{
  __shared__ __align__(16) short h0ring[4*1024];   // 8 KB: 4 slots x [16][64]
  __shared__ __align__(16) short h1buf [2*1024];   // 4 KB: 2 bufs
  __shared__ __align__(16) f32x4 stage[8*128];     // 16 KB: [wave][hl(2)][cell(64)]
  __shared__ __align__(16) float h1f[BB*Hh];
  __shared__ float zs[BB*32];
  __shared__ int flags[2];                          // c0done, c1done

  const int tid  = threadIdx.x;
  const int lane = tid & 63;
  const int wid  = tid >> 6;        // 0..7
  const int lr   = lane & 15;
  const int lg   = lane >> 4;
  const int eng  = wid >> 2;        // 0 = L0 engine, 1 = L1 engine
  const int w4   = wid & 3;
  const int b0   = blockIdx.x * BB;

  // per-lane cell: p = lane>>4, jloc = (lane>>2)&3, bs = lane&3
  const int c_p  = lane >> 4;
  const int c_j  = (lane >> 2) & 3;
  const int c_bs = lane & 3;
  const int u_j  = w4*16 + c_p*4 + c_j;

  // zero h0ring + h1buf (12 KB = 3072 ints)
  {
    int* hz = (int*)h0ring;
    #pragma unroll
    for (int i = 0; i < 4; ++i) hz[tid + i*NT] = 0;
    int* h1z = (int*)h1buf;
    h1z[tid] = 0; h1z[tid + NT] = 0;
  }
  if (tid == 0){ flags[0] = 0; flags[1] = 0; }

  // loop-invariant LDS offsets
  const int boff0 = (lr*128 + lg*16)      ^ ((lr&7)<<4);     // B kt=0 (bytes, plane-rel)
  const int boff1 = (lr*128 + 64 + lg*16) ^ ((lr&7)<<4);     // B kt=1
  const int whi   = (c_bs*128     + u_j*2) ^ (c_bs<<4);      // h_hi write
  const int wlo   = ((c_bs+4)*128 + u_j*2) ^ ((c_bs+4)<<4);  // h_lo write
  const int stW   = wid*128 + ((lr>>2)&1)*64 + lg*4 + (lr&3);// stage write base (lr<8)
  const int stR   = wid*128 + lane;                          // stage read (hi; +64 lo)

  __syncthreads();

  if (eng == 0){
    // ================= L0 engine: h0(t) = LSTM0(h0(t-1), x(t)) =================
    bf16x8 A0[4][2][2];   // [p][kt][hi/lo] Whh0, tiles gp = w4*4+p
    #pragma unroll
    for (int p = 0; p < 4; ++p){
      const int m = (lr&3)*64 + w4*16 + p*4 + (lr>>2);
      #pragma unroll
      for (int kt = 0; kt < 2; ++kt){
        const int off = m*64 + kt*32 + lg*8;
        float wbuf[8];
        *(float4*)&wbuf[0] = *(const float4*)&Whh0[off];
        *(float4*)&wbuf[4] = *(const float4*)&Whh0[off+4];
        split8(wbuf, A0[p][kt][0], A0[p][kt][1]);
      }
    }
    float bias_g[4], w0r[24];
    #pragma unroll
    for (int gt = 0; gt < 4; ++gt){
      const int row = gt*64 + u_j;
      bias_g[gt] = bih0[row] + bhh0[row];
      #pragma unroll
      for (int d = 0; d < Dd; ++d) w0r[gt*6+d] = Wih0[row*Dd + d];
    }
    const float2* px2 = (const float2*)(x + (size_t)(b0 + c_bs) * (Tt*Dd));
    float creg = 0.f;

    // prologue t=0: h0(0) from x(0) only
    {
      float2 xa = px2[0], xb = px2[1], xc = px2[2];
      float s[4];
      #pragma unroll
      for (int gt = 0; gt < 4; ++gt)
        s[gt] = bias_g[gt] + w0r[gt*6+0]*xa.x + w0r[gt*6+1]*xa.y
              + w0r[gt*6+2]*xb.x + w0r[gt*6+3]*xb.y
              + w0r[gt*6+4]*xc.x + w0r[gt*6+5]*xc.y;
      float iv = sigm(s[0]), fv = sigm(s[1]), gv = tanh_(s[2]), ov = sigm(s[3]);
      creg = fv*creg + iv*gv;
      float hval = ov * tanh_(creg);
      unsigned short hh, hl; splitH(hval, hh, hl);
      char* hw = (char*)h0ring;            // slot 0
      *(short*)(hw + whi) = (short)hh;
      *(short*)(hw + wlo) = (short)hl;
      incFlag(&flags[0], lane);
    }

    #pragma unroll 1
    for (int t = 1; t < Tt; ++t){
      spinGE(&flags[0], 4*t);                       // h0(t-1) fully written
      const char* hb = (const char*)h0ring + ((t-1)&3)*2048;
      bf16x8 b00 = *(const bf16x8*)(hb + boff0);
      bf16x8 b01 = *(const bf16x8*)(hb + boff1);
      float2 x0 = px2[t*3], x1 = px2[t*3+1], x2 = px2[t*3+2];

      f32x4 a[4];
      #pragma unroll
      for (int p = 0; p < 4; ++p) a[p] = (f32x4){0,0,0,0};
      #pragma unroll
      for (int p = 0; p < 4; ++p) MF(A0[p][0][0], b00, a[p]);
      #pragma unroll
      for (int p = 0; p < 4; ++p) MF(A0[p][1][0], b01, a[p]);
      #pragma unroll
      for (int p = 0; p < 4; ++p) MF(A0[p][0][1], b00, a[p]);
      #pragma unroll
      for (int p = 0; p < 4; ++p) MF(A0[p][1][1], b01, a[p]);

      if (lr < 8){                                  // stage both hi/lo halves
        stage[stW     ] = a[0];
        stage[stW + 16] = a[1];
        stage[stW + 32] = a[2];
        stage[stW + 48] = a[3];
      }
      f32x4 gh = stage[stR];
      f32x4 gl = stage[stR + 64];
      float s0 = gh[0] + gl[0] + bias_g[0]
               + w0r[ 0]*x0.x + w0r[ 1]*x0.y + w0r[ 2]*x1.x
               + w0r[ 3]*x1.y + w0r[ 4]*x2.x + w0r[ 5]*x2.y;
      float s1 = gh[1] + gl[1] + bias_g[1]
               + w0r[ 6]*x0.x + w0r[ 7]*x0.y + w0r[ 8]*x1.x
               + w0r[ 9]*x1.y + w0r[10]*x2.x + w0r[11]*x2.y;
      float s2 = gh[2] + gl[2] + bias_g[2]
               + w0r[12]*x0.x + w0r[13]*x0.y + w0r[14]*x1.x
               + w0r[15]*x1.y + w0r[16]*x2.x + w0r[17]*x2.y;
      float s3 = gh[3] + gl[3] + bias_g[3]
               + w0r[18]*x0.x + w0r[19]*x0.y + w0r[20]*x1.x
               + w0r[21]*x1.y + w0r[22]*x2.x + w0r[23]*x2.y;
      float iv = sigm(s0), fv = sigm(s1), gv = tanh_(s2), ov = sigm(s3);
      creg = fv*creg + iv*gv;
      float hval = ov * tanh_(creg);
      unsigned short hh, hl; splitH(hval, hh, hl);

      if (t >= 4) spinGE(&flags[1], 4*(t-3));       // slot t%4 free (L1 consumed h0(t-4))
      char* hw = (char*)h0ring + (t&3)*2048;
      *(short*)(hw + whi) = (short)hh;
      *(short*)(hw + wlo) = (short)hl;
      incFlag(&flags[0], lane);
    }
  } else {
    // ====== L1 engine: h1(t) = LSTM1(h1(t-1), h0(t)); no x-projection ======
    bf16x8 A1i[4][2][2], A1h[4][2][2];
    #pragma unroll
    for (int p = 0; p < 4; ++p){
      const int m = (lr&3)*64 + w4*16 + p*4 + (lr>>2);
      #pragma unroll
      for (int kt = 0; kt < 2; ++kt){
        const int off = m*64 + kt*32 + lg*8;
        float wbuf[8];
        *(float4*)&wbuf[0] = *(const float4*)&Wih1[off];
        *(float4*)&wbuf[4] = *(const float4*)&Wih1[off+4];
        split8(wbuf, A1i[p][kt][0], A1i[p][kt][1]);
        *(float4*)&wbuf[0] = *(const float4*)&Whh1[off];
        *(float4*)&wbuf[4] = *(const float4*)&Whh1[off+4];
        split8(wbuf, A1h[p][kt][0], A1h[p][kt][1]);
      }
    }
    float bias_g[4];
    #pragma unroll
    for (int gt = 0; gt < 4; ++gt){
      const int row = gt*64 + u_j;
      bias_g[gt] = bih1[row] + bhh1[row];
    }
    float creg = 0.f;

    #pragma unroll 1
    for (int t = 0; t < Tt; ++t){
      spinGE(&flags[0], 4*(t+1));                   // h0(t) ready
      spinGE(&flags[1], 4*t);                       // h1(t-1) ready + buf rotation safe
      const char* hb0 = (const char*)h0ring + (t&3)*2048;
      const char* hb1 = (const char*)h1buf + ((t&1)^1)*2048;
      bf16x8 b00 = *(const bf16x8*)(hb0 + boff0);
      bf16x8 b01 = *(const bf16x8*)(hb0 + boff1);
      bf16x8 b10 = *(const bf16x8*)(hb1 + boff0);
      bf16x8 b11 = *(const bf16x8*)(hb1 + boff1);

      f32x4 ai[4], ah[4];
      #pragma unroll
      for (int p = 0; p < 4; ++p){ ai[p] = (f32x4){0,0,0,0}; ah[p] = (f32x4){0,0,0,0}; }
      #pragma unroll
      for (int p = 0; p < 4; ++p){ MF(A1i[p][0][0], b00, ai[p]); MF(A1h[p][0][0], b10, ah[p]); }
      #pragma unroll
      for (int p = 0; p < 4; ++p){ MF(A1i[p][1][0], b01, ai[p]); MF(A1h[p][1][0], b11, ah[p]); }
      #pragma unroll
      for (int p = 0; p < 4; ++p){ MF(A1i[p][0][1], b00, ai[p]); MF(A1h[p][0][1], b10, ah[p]); }
      #pragma unroll
      for (int p = 0; p < 4; ++p){ MF(A1i[p][1][1], b01, ai[p]); MF(A1h[p][1][1], b11, ah[p]); }

      if (lr < 8){
        stage[stW     ] = ai[0] + ah[0];
        stage[stW + 16] = ai[1] + ah[1];
        stage[stW + 32] = ai[2] + ah[2];
        stage[stW + 48] = ai[3] + ah[3];
      }
      f32x4 gh = stage[stR];
      f32x4 gl = stage[stR + 64];
      float s0 = gh[0] + gl[0] + bias_g[0];
      float s1 = gh[1] + gl[1] + bias_g[1];
      float s2 = gh[2] + gl[2] + bias_g[2];
      float s3 = gh[3] + gl[3] + bias_g[3];
      float iv = sigm(s0), fv = sigm(s1), gv = tanh_(s2), ov = sigm(s3);
      creg = fv*creg + iv*gv;
      float hval = ov * tanh_(creg);
      if (t == Tt-1) h1f[c_bs*64 + u_j] = hval;
      unsigned short hh, hl; splitH(hval, hh, hl);
      char* hw = (char*)h1buf + (t&1)*2048;
      *(short*)(hw + whi) = (short)hh;
      *(short*)(hw + wlo) = (short)hl;
      incFlag(&flags[1], lane);
    }
  }

  __syncthreads();

  // ---- MLP head on h1(T-1) ----
  if (tid < BB*32){
    const int bsh = tid >> 5, m = tid & 31;
    float acc = b1[m];
    #pragma unroll
    for (int j = 0; j < Hh; ++j) acc += W1[m*Hh + j] * h1f[bsh*64 + j];
    zs[bsh*32 + m] = fmaxf(acc, 0.f);
  }
  __syncthreads();
  if (tid < BB){
    float acc = b2[0];
    #pragma unroll
    for (int m = 0; m < 32; ++m) acc += W2[m] * zs[tid*32 + m];
    out[b0 + tid] = sigm(acc);
  }
}

extern "C" void kernel_launch(void* const* d_in, const int* in_sizes, int n_in,
                              void* d_out, int out_size, void* d_ws, size_t ws_size,
                              hipStream_t stream) {
  const float* x    = (const float*)d_in[0];
  const float* Wih0 = (const float*)d_in[1];
  const float* Whh0 = (const float*)d_in[2];
  const float* bih0 = (const float*)d_in[3];
  const float* bhh0 = (const float*)d_in[4];
  const float* Wih1 = (const float*)d_in[5];
  const float* Whh1 = (const float*)d_in[6];
  const float* bih1 = (const float*)d_in[7];
  const float* bhh1 = (const float*)d_in[8];
  const float* W1   = (const float*)d_in[9];
  const float* b1   = (const float*)d_in[10];
  const float* W2   = (const float*)d_in[11];
  const float* b2   = (const float*)d_in[12];

  const int B = in_sizes[0] / (Tt*Dd);   // 1024
  dim3 grid(B / BB), block(NT);
  hipLaunchKernelGGL(lstm2_ps, grid, block, 0, stream,
                     x, Wih0, Whh0, bih0, bhh0, Wih1, Whh1, bih1, bhh1,
                     W1, b1, W2, b2, (float*)d_out);
}